// Round 2
// baseline (416.444 us; speedup 1.0000x reference)
//
#include <hip/hip_runtime.h>
#include <hip/hip_bf16.h>
#include <cstdint>
#include <cstddef>

// Shapes fixed by the problem: B=4, N=16384, C=256, H=4, D=64.
#define SEQ   16384
#define CHN   256

typedef __attribute__((ext_vector_type(8))) short  short8;   // 8 bf16 (4 VGPRs)
typedef __attribute__((ext_vector_type(4))) float  f32x4;    // MFMA C/D

static __device__ __forceinline__ unsigned short f2bf(float f) {
    unsigned int u = __builtin_bit_cast(unsigned int, f);
    u += 0x7fffu + ((u >> 16) & 1u);            // round-to-nearest-even
    return (unsigned short)(u >> 16);
}
static __device__ __forceinline__ float bf2f(unsigned short h) {
    unsigned int u = ((unsigned int)h) << 16;
    return __builtin_bit_cast(float, u);
}
static __device__ __forceinline__ float gelu_exact(float x) {
    return 0.5f * x * (1.0f + erff(x * 0.70710678118654752f));
}
// XOR-swizzled ushort index for [R][64]-bf16 LDS tiles (128 B rows).
static __device__ __forceinline__ int swz_us(int row, int kbyte) {
    return (row * 128 + (kbyte ^ ((row & 7) << 4))) >> 1;
}
// XOR-swizzled ushort index for [R][256]-bf16 LDS tiles (512 B rows).
// Rows are bank-aliased (512 % 128 == 0); XOR bits 4..6 spreads 8 rows
// across the 128 B bank span -> 2-way max on 16-lane row-column reads.
static __device__ __forceinline__ int swzA(int row, int kbyte) {
    return (row * 512 + (kbyte ^ ((row & 7) << 4))) >> 1;
}

// ---------------------------------------------------------------- prep ----
__global__ __launch_bounds__(256) void prep_kernel(
    const float* __restrict__ Wq, const float* __restrict__ Wk,
    const float* __restrict__ Wv, const float* __restrict__ Wp,
    unsigned short* __restrict__ Wqt, unsigned short* __restrict__ Wkt,
    unsigned short* __restrict__ Wvt, unsigned short* __restrict__ Wpt,
    float* __restrict__ KV, float* __restrict__ Ksum)
{
    const int idx = blockIdx.x * 256 + threadIdx.x;   // 0..65535
    const int n = idx >> 8, k = idx & 255;
    const int src = k * 256 + n;                      // W^T[n][k] = W[k][n]
    Wqt[idx] = f2bf(Wq[src]);
    Wkt[idx] = f2bf(Wk[src]);
    Wvt[idx] = f2bf(Wv[src]);
    Wpt[idx] = f2bf(Wp[src]);
    KV[idx] = 0.0f;                                   // 16*64*64 = 65536
    if (idx < 1024) Ksum[idx] = 0.0f;                 // 16*64
}

// ------------------------------------------------------------ QKV GEMM ----
// grid (512): one block per 128-row tile. Stage x once (f32->bf16, full
// K=256, 64 KB LDS), then loop all 6 output tiles (Q|K|V x 2 col-halves)
// with B fragments loaded directly from global (weights are L2-resident).
__global__ __launch_bounds__(256) void qkv_gemm(
    const float* __restrict__ x, const float* __restrict__ my,
    const unsigned short* __restrict__ Wqt, const unsigned short* __restrict__ Wkt,
    const unsigned short* __restrict__ Wvt,
    const float* __restrict__ bq, const float* __restrict__ bk,
    const float* __restrict__ bv,
    unsigned short* __restrict__ Qb, unsigned short* __restrict__ Kb,
    unsigned short* __restrict__ Vb)
{
    __shared__ unsigned short As[128 * 256];   // 64 KB
    __shared__ float mys[128];
    const int t = threadIdx.x;
    const long row0 = (long)blockIdx.x * 128;
    const int lane = t & 63, wave = t >> 6, wm = wave >> 1, wn = wave & 1;

    // stage A: x tile f32 -> bf16 LDS, swizzled. 32 float4 / thread.
    #pragma unroll
    for (int it = 0; it < 32; ++it) {
        const int idx = it * 256 + t;           // 0..8191, 4 floats each
        const int r = idx >> 6, c4 = (idx & 63) * 4;
        const float4 v = *(const float4*)(x + (row0 + r) * 256 + c4);
        uint2 pk;
        pk.x = (unsigned int)f2bf(v.x) | ((unsigned int)f2bf(v.y) << 16);
        pk.y = (unsigned int)f2bf(v.z) | ((unsigned int)f2bf(v.w) << 16);
        *(uint2*)&As[swzA(r, c4 * 2)] = pk;
    }
    if (t < 128) mys[t] = my[row0 + t];
    __syncthreads();

    #pragma unroll 1
    for (int ot = 0; ot < 6; ++ot) {
        const int mat  = ot >> 1;
        const int col0 = (ot & 1) * 128;
        const unsigned short* Wt = (mat == 0) ? Wqt : (mat == 1) ? Wkt : Wvt;
        const float* bias        = (mat == 0) ? bq  : (mat == 1) ? bk  : bv;
        unsigned short* Ob       = (mat == 0) ? Qb  : (mat == 1) ? Kb  : Vb;

        f32x4 acc[4][4];
        #pragma unroll
        for (int i = 0; i < 4; ++i)
            #pragma unroll
            for (int j = 0; j < 4; ++j) acc[i][j] = (f32x4)0.0f;

        #pragma unroll
        for (int kk = 0; kk < 8; ++kk) {
            const int ke = kk * 32 + (lane >> 4) * 8;     // element k
            short8 af[4], bfr[4];
            #pragma unroll
            for (int mi = 0; mi < 4; ++mi) {
                const int r = wm * 64 + mi * 16 + (lane & 15);
                af[mi] = *(const short8*)&As[swzA(r, ke * 2)];
            }
            #pragma unroll
            for (int ni = 0; ni < 4; ++ni) {
                const int n = col0 + wn * 64 + ni * 16 + (lane & 15);
                bfr[ni] = *(const short8*)(Wt + (size_t)n * 256 + ke);
            }
            #pragma unroll
            for (int mi = 0; mi < 4; ++mi)
                #pragma unroll
                for (int ni = 0; ni < 4; ++ni)
                    acc[mi][ni] = __builtin_amdgcn_mfma_f32_16x16x32_bf16(
                        af[mi], bfr[ni], acc[mi][ni], 0, 0, 0);
        }

        #pragma unroll
        for (int ni = 0; ni < 4; ++ni) {
            const int coll = col0 + wn * 64 + ni * 16 + (lane & 15);
            const float bc = bias[coll];
            #pragma unroll
            for (int mi = 0; mi < 4; ++mi) {
                const int lr0 = wm * 64 + mi * 16 + ((lane >> 4) << 2);
                #pragma unroll
                for (int r = 0; r < 4; ++r) {
                    const int lr = lr0 + r;
                    float val = acc[mi][ni][r] + bc;
                    if (mat == 0)      val = gelu_exact(val) + 1.0f;
                    else if (mat == 1) val = gelu_exact(val * mys[lr]) + 1.0f;
                    else               val = val * mys[lr];
                    Ob[(row0 + lr) * 256 + coll] = f2bf(val);
                }
            }
        }
    }
}

// ----------------------------------------------------------- KV reduce ----
// grid (64, 16): x = m-chunk (256 rows), y = (b*4+h). Vector FMA outer
// product; fp32 atomic accumulation into KV[bh][d][e] and Ksum[bh][d].
__global__ __launch_bounds__(256) void kv_reduce(
    const unsigned short* __restrict__ Kb, const unsigned short* __restrict__ Vb,
    float* __restrict__ KV, float* __restrict__ Ksum)
{
    __shared__ float kf[16][64];
    __shared__ float vf[16][64];
    const int t = threadIdx.x;
    const int bh = blockIdx.y;
    const long base = (long)(bh >> 2) * SEQ * 256 + (bh & 3) * 64;
    const long m0 = (long)blockIdx.x * 256;
    const int d0 = (t >> 4) * 4, e0 = (t & 15) * 4;
    const int sr = t >> 4, swhich = (t >> 3) & 1, sseg = t & 7;
    float acc[4][4] = {};
    float ks[4] = {};
    for (int it = 0; it < 16; ++it) {
        const long row = m0 + it * 16 + sr;
        const unsigned short* src = (swhich ? Vb : Kb) + base + row * 256 + sseg * 8;
        const uint4 raw = *(const uint4*)src;
        const unsigned short* rh = (const unsigned short*)&raw;
        float* dst = swhich ? &vf[sr][sseg * 8] : &kf[sr][sseg * 8];
        #pragma unroll
        for (int j = 0; j < 8; ++j) dst[j] = bf2f(rh[j]);
        __syncthreads();
        #pragma unroll
        for (int mm = 0; mm < 16; ++mm) {
            const float4 kd = *(const float4*)&kf[mm][d0];
            const float4 ve = *(const float4*)&vf[mm][e0];
            const float k4[4] = {kd.x, kd.y, kd.z, kd.w};
            const float v4[4] = {ve.x, ve.y, ve.z, ve.w};
            #pragma unroll
            for (int i = 0; i < 4; ++i)
                #pragma unroll
                for (int j = 0; j < 4; ++j) acc[i][j] += k4[i] * v4[j];
            if ((t & 15) == 0) {
                #pragma unroll
                for (int i = 0; i < 4; ++i) ks[i] += k4[i];
            }
        }
        __syncthreads();
    }
    #pragma unroll
    for (int i = 0; i < 4; ++i)
        #pragma unroll
        for (int j = 0; j < 4; ++j)
            atomicAdd(&KV[((size_t)bh * 64 + d0 + i) * 64 + e0 + j], acc[i][j]);
    if ((t & 15) == 0) {
        #pragma unroll
        for (int i = 0; i < 4; ++i) atomicAdd(&Ksum[bh * 64 + d0 + i], ks[i]);
    }
}

// ---------------------------------------------------------------- attn ----
// grid (512): one 128-row tile; loops the 4 heads. attn = (Q@KV)*mx/denom.
__global__ __launch_bounds__(256) void attn_kernel(
    const unsigned short* __restrict__ Qb, const float* __restrict__ KV,
    const float* __restrict__ Ksum, const float* __restrict__ mx,
    unsigned short* __restrict__ Ab)
{
    __shared__ unsigned short Qs[128 * 64];
    __shared__ unsigned short KVT[64 * 64];
    __shared__ float ksh[64];
    __shared__ float sden[128];
    const int t = threadIdx.x;
    const long row0 = (long)blockIdx.x * 128;
    const int b = (int)(row0 >> 14);
    const int lane = t & 63, wave = t >> 6, wm = wave >> 1, wn = wave & 1;

    for (int h = 0; h < 4; ++h) {
        const int bh = b * 4 + h;
        // stage Q_h [128][64]
        #pragma unroll
        for (int it = 0; it < 4; ++it) {
            const int idx = it * 256 + t;
            const int r = idx >> 3, c8 = (idx & 7) * 8;
            const uint4 v = *(const uint4*)(Qb + (row0 + r) * 256 + h * 64 + c8);
            *(uint4*)&Qs[swz_us(r, c8 * 2)] = v;
        }
        // stage KV^T [e][d] (bf16, swizzled)
        {
            const int e = t & 63, dg = t >> 6;
            #pragma unroll
            for (int i = 0; i < 16; ++i) {
                const int d = dg * 16 + i;
                const float v = KV[((size_t)bh * 64 + d) * 64 + e];
                KVT[(e * 128 + ((d * 2) ^ ((e & 7) << 4))) >> 1] = f2bf(v);
            }
        }
        if (t < 64) ksh[t] = Ksum[bh * 64 + t];
        __syncthreads();
        // denom per row; sden = mask_x / denom
        if (t < 128) {
            float s = 0.0f;
            for (int d = 0; d < 64; ++d)
                s += bf2f(Qs[swz_us(t, d * 2)]) * ksh[d];
            sden[t] = mx[row0 + t] / s;
        }
        __syncthreads();
        // MFMA: per wave 64m x 32e, k = 64 (two K=32 steps)
        f32x4 acc[4][2];
        #pragma unroll
        for (int i = 0; i < 4; ++i) { acc[i][0] = (f32x4)0.0f; acc[i][1] = (f32x4)0.0f; }
        #pragma unroll
        for (int kk = 0; kk < 2; ++kk) {
            const int kbyte = kk * 64 + (lane >> 4) * 16;
            short8 af[4], bfr[2];
            #pragma unroll
            for (int mi = 0; mi < 4; ++mi) {
                const int r = wm * 64 + mi * 16 + (lane & 15);
                af[mi] = *(const short8*)&Qs[swz_us(r, kbyte)];
            }
            #pragma unroll
            for (int ni = 0; ni < 2; ++ni) {
                const int e = wn * 32 + ni * 16 + (lane & 15);
                bfr[ni] = *(const short8*)&KVT[swz_us(e, kbyte)];
            }
            #pragma unroll
            for (int mi = 0; mi < 4; ++mi)
                #pragma unroll
                for (int ni = 0; ni < 2; ++ni)
                    acc[mi][ni] = __builtin_amdgcn_mfma_f32_16x16x32_bf16(
                        af[mi], bfr[ni], acc[mi][ni], 0, 0, 0);
        }
        #pragma unroll
        for (int ni = 0; ni < 2; ++ni) {
            const int e = wn * 32 + ni * 16 + (lane & 15);
            #pragma unroll
            for (int mi = 0; mi < 4; ++mi) {
                const int lr0 = wm * 64 + mi * 16 + ((lane >> 4) << 2);
                #pragma unroll
                for (int r = 0; r < 4; ++r) {
                    const int lr = lr0 + r;
                    const float val = acc[mi][ni][r] * sden[lr];
                    Ab[(row0 + lr) * 256 + h * 64 + e] = f2bf(val);
                }
            }
        }
        __syncthreads();   // LDS reused next head
    }
}

// ------------------------------------------------------------ out proj ----
// grid (512): one block per 128-row tile; stage A once, loop 2 col-tiles
// with B fragments direct from global (Wp is L2-resident).
__global__ __launch_bounds__(256) void proj_gemm(
    const unsigned short* __restrict__ Ab, const unsigned short* __restrict__ Wpt,
    const float* __restrict__ bp, float* __restrict__ out)
{
    __shared__ unsigned short As[128 * 256];   // 64 KB
    const int t = threadIdx.x;
    const long row0 = (long)blockIdx.x * 128;
    const int lane = t & 63, wave = t >> 6, wm = wave >> 1, wn = wave & 1;

    #pragma unroll
    for (int it = 0; it < 16; ++it) {
        const int idx = it * 256 + t;           // 0..4095, 8 ushorts each
        const int r = idx >> 5, c8 = (idx & 31) * 8;
        const uint4 v = *(const uint4*)(Ab + (row0 + r) * 256 + c8);
        *(uint4*)&As[swzA(r, c8 * 2)] = v;
    }
    __syncthreads();

    #pragma unroll 1
    for (int ct = 0; ct < 2; ++ct) {
        const int col0 = ct * 128;
        f32x4 acc[4][4];
        #pragma unroll
        for (int i = 0; i < 4; ++i)
            #pragma unroll
            for (int j = 0; j < 4; ++j) acc[i][j] = (f32x4)0.0f;

        #pragma unroll
        for (int kk = 0; kk < 8; ++kk) {
            const int ke = kk * 32 + (lane >> 4) * 8;
            short8 af[4], bfr[4];
            #pragma unroll
            for (int mi = 0; mi < 4; ++mi) {
                const int r = wm * 64 + mi * 16 + (lane & 15);
                af[mi] = *(const short8*)&As[swzA(r, ke * 2)];
            }
            #pragma unroll
            for (int ni = 0; ni < 4; ++ni) {
                const int n = col0 + wn * 64 + ni * 16 + (lane & 15);
                bfr[ni] = *(const short8*)(Wpt + (size_t)n * 256 + ke);
            }
            #pragma unroll
            for (int mi = 0; mi < 4; ++mi)
                #pragma unroll
                for (int ni = 0; ni < 4; ++ni)
                    acc[mi][ni] = __builtin_amdgcn_mfma_f32_16x16x32_bf16(
                        af[mi], bfr[ni], acc[mi][ni], 0, 0, 0);
        }

        #pragma unroll
        for (int ni = 0; ni < 4; ++ni) {
            const int coll = col0 + wn * 64 + ni * 16 + (lane & 15);
            const float bc = bp[coll];
            #pragma unroll
            for (int mi = 0; mi < 4; ++mi) {
                const int lr0 = wm * 64 + mi * 16 + ((lane >> 4) << 2);
                #pragma unroll
                for (int r = 0; r < 4; ++r) {
                    const long grow = row0 + lr0 + r;
                    out[grow * 256 + coll] = acc[mi][ni][r] + bc;
                }
            }
        }
    }
}

// -------------------------------------------------------------- launch ----
extern "C" void kernel_launch(void* const* d_in, const int* in_sizes, int n_in,
                              void* d_out, int out_size, void* d_ws, size_t ws_size,
                              hipStream_t stream)
{
    (void)in_sizes; (void)n_in; (void)out_size; (void)ws_size;
    const float* x  = (const float*)d_in[0];
    const float* mx = (const float*)d_in[1];
    const float* my = (const float*)d_in[2];
    const float* Wq = (const float*)d_in[3];
    const float* bq = (const float*)d_in[4];
    const float* Wk = (const float*)d_in[5];
    const float* bk = (const float*)d_in[6];
    const float* Wv = (const float*)d_in[7];
    const float* bv = (const float*)d_in[8];
    const float* Wp = (const float*)d_in[9];
    const float* bp = (const float*)d_in[10];
    float* out = (float*)d_out;

    const size_t nelem = (size_t)4 * SEQ * CHN;      // 16,777,216
    char* w = (char*)d_ws;
    unsigned short* Qb  = (unsigned short*)w; w += nelem * 2;
    unsigned short* Kb  = (unsigned short*)w; w += nelem * 2;
    unsigned short* Vb  = (unsigned short*)w; w += nelem * 2;
    unsigned short* Wqt = (unsigned short*)w; w += 131072;
    unsigned short* Wkt = (unsigned short*)w; w += 131072;
    unsigned short* Wvt = (unsigned short*)w; w += 131072;
    unsigned short* Wpt = (unsigned short*)w; w += 131072;
    float* KV   = (float*)w; w += 262144;
    float* Ksum = (float*)w; w += 4096;
    unsigned short* Ab = Kb;   // alias: Kb is dead after kv_reduce

    prep_kernel<<<256, 256, 0, stream>>>(Wq, Wk, Wv, Wp, Wqt, Wkt, Wvt, Wpt, KV, Ksum);
    qkv_gemm<<<512, 256, 0, stream>>>(x, my, Wqt, Wkt, Wvt, bq, bk, bv, Qb, Kb, Vb);
    kv_reduce<<<dim3(64, 16), 256, 0, stream>>>(Kb, Vb, KV, Ksum);
    attn_kernel<<<512, 256, 0, stream>>>(Qb, KV, Ksum, mx, Ab);
    proj_gemm<<<512, 256, 0, stream>>>(Ab, Wpt, bp, out);
}

// Round 4
// 349.875 us; speedup vs baseline: 1.1903x; 1.1903x over previous
//
#include <hip/hip_runtime.h>
#include <hip/hip_bf16.h>
#include <cstdint>
#include <cstddef>

// Shapes fixed by the problem: B=4, N=16384, C=256, H=4, D=64.
#define SEQ   16384
#define CHN   256

typedef __attribute__((ext_vector_type(8))) short  short8;   // 8 bf16 (4 VGPRs)
typedef __attribute__((ext_vector_type(4))) float  f32x4;    // MFMA C/D

#define AS1 __attribute__((address_space(1)))
#define AS3 __attribute__((address_space(3)))
static __device__ __forceinline__ void gl_lds16(const void* g, void* l) {
    // async global->LDS, 16 B per lane; LDS dest = wave base + lane*16
    __builtin_amdgcn_global_load_lds((const AS1 void*)g, (AS3 void*)l, 16, 0, 0);
}

static __device__ __forceinline__ unsigned short f2bf(float f) {
    unsigned int u = __builtin_bit_cast(unsigned int, f);
    u += 0x7fffu + ((u >> 16) & 1u);            // round-to-nearest-even
    return (unsigned short)(u >> 16);
}
static __device__ __forceinline__ float bf2f(unsigned short h) {
    unsigned int u = ((unsigned int)h) << 16;
    return __builtin_bit_cast(float, u);
}
static __device__ __forceinline__ float gelu_exact(float x) {
    return 0.5f * x * (1.0f + erff(x * 0.70710678118654752f));
}
// XOR-swizzled ushort index for [R][64]-bf16 LDS tiles (used by attn only).
static __device__ __forceinline__ int swz_us(int row, int kbyte) {
    return (row * 128 + (kbyte ^ ((row & 7) << 4))) >> 1;
}

// ------------------------------------------------------------- convert ----
// x f32 -> bf16, 16.7M elems. 2048 blocks x 256 threads x 4 groups of 8.
__global__ __launch_bounds__(256) void cvt_kernel(
    const float* __restrict__ x, unsigned short* __restrict__ xb)
{
    const int t0 = blockIdx.x * 256 + threadIdx.x;
    #pragma unroll
    for (int i = 0; i < 4; ++i) {
        const long g = (long)t0 + (long)i * 524288;   // 8-elem group id
        const float4 a = *(const float4*)(x + g * 8);
        const float4 b = *(const float4*)(x + g * 8 + 4);
        uint4 pk;
        pk.x = (unsigned int)f2bf(a.x) | ((unsigned int)f2bf(a.y) << 16);
        pk.y = (unsigned int)f2bf(a.z) | ((unsigned int)f2bf(a.w) << 16);
        pk.z = (unsigned int)f2bf(b.x) | ((unsigned int)f2bf(b.y) << 16);
        pk.w = (unsigned int)f2bf(b.z) | ((unsigned int)f2bf(b.w) << 16);
        *(uint4*)(xb + g * 8) = pk;
    }
}

// ---------------------------------------------------------------- prep ----
// Wcat rows: [0,256)=Wq^T, [256,512)=Wk^T, [512,768)=Wv^T. Plus Wp^T, zero KV.
__global__ __launch_bounds__(256) void prep_kernel(
    const float* __restrict__ Wq, const float* __restrict__ Wk,
    const float* __restrict__ Wv, const float* __restrict__ Wp,
    unsigned short* __restrict__ Wcat, unsigned short* __restrict__ Wpt,
    float* __restrict__ KV, float* __restrict__ Ksum)
{
    const int idx = blockIdx.x * 256 + threadIdx.x;   // 0..65535
    const int n = idx >> 8, k = idx & 255;
    const int src = k * 256 + n;                      // W^T[n][k] = W[k][n]
    Wcat[idx]          = f2bf(Wq[src]);
    Wcat[65536 + idx]  = f2bf(Wk[src]);
    Wcat[131072 + idx] = f2bf(Wv[src]);
    Wpt[idx]           = f2bf(Wp[src]);
    KV[idx] = 0.0f;                                   // 16*64*64 = 65536
    if (idx < 1024) Ksum[idx] = 0.0f;                 // 16*64
}

// ------------------------------------------------------------ QKV GEMM ----
// m97 template: 128x128 tile, BK=64, 4 waves, global_load_lds staging,
// single-buffered LDS, 2 barriers per K-step. Grid 3072 = 512 row-tiles
// x 6 col-tiles of the fused N=768 (Q|K|V) output; XCD-swizzled so the 6
// blocks sharing a row-tile land on one XCD (xb tile stays in its L2).
__global__ __launch_bounds__(256) void qkv_gemm(
    const unsigned short* __restrict__ xb, const float* __restrict__ my,
    const unsigned short* __restrict__ Wcat,
    const float* __restrict__ bq, const float* __restrict__ bk,
    const float* __restrict__ bv,
    unsigned short* __restrict__ Qb, unsigned short* __restrict__ Kb,
    unsigned short* __restrict__ Vb)
{
    __shared__ unsigned short As[128 * 64];   // 16 KB, linear [row][64]
    __shared__ unsigned short Bs[128 * 64];   // 16 KB, linear [n][64]
    __shared__ float mys[128];
    const int t = threadIdx.x;
    const int nwg = 3072, phys = blockIdx.x;
    const int l = (phys & 7) * (nwg >> 3) + (phys >> 3);   // XCD swizzle
    const int rt = l / 6, ct = l % 6;
    const long row0 = (long)rt * 128;
    const int  ncol0 = ct * 128;              // row in Wcat / fused col
    const int  mat = ct >> 1;
    const int lane = t & 63, wave = t >> 6, wm = wave >> 1, wn = wave & 1;

    if (t < 128) mys[t] = my[row0 + t];

    f32x4 acc[4][4];
    #pragma unroll
    for (int i = 0; i < 4; ++i)
        #pragma unroll
        for (int j = 0; j < 4; ++j) acc[i][j] = (f32x4)0.0f;

    for (int k0 = 0; k0 < 256; k0 += 64) {
        // stage A: 1024 16B-chunks; chunk c -> row c>>3, k-chunk c&7
        #pragma unroll
        for (int i = 0; i < 4; ++i) {
            const int c = i * 256 + t;
            gl_lds16(xb + (row0 + (c >> 3)) * 256 + k0 + (c & 7) * 8, &As[c * 8]);
        }
        #pragma unroll
        for (int i = 0; i < 4; ++i) {
            const int c = i * 256 + t;
            gl_lds16(Wcat + (size_t)(ncol0 + (c >> 3)) * 256 + k0 + (c & 7) * 8, &Bs[c * 8]);
        }
        __syncthreads();
        #pragma unroll
        for (int kk = 0; kk < 2; ++kk) {
            short8 af[4], bfr[4];
            #pragma unroll
            for (int mi = 0; mi < 4; ++mi) {
                const int r = wm * 64 + mi * 16 + (lane & 15);
                af[mi] = *(const short8*)&As[r * 64 + kk * 32 + (lane >> 4) * 8];
            }
            #pragma unroll
            for (int ni = 0; ni < 4; ++ni) {
                const int n = wn * 64 + ni * 16 + (lane & 15);
                bfr[ni] = *(const short8*)&Bs[n * 64 + kk * 32 + (lane >> 4) * 8];
            }
            #pragma unroll
            for (int mi = 0; mi < 4; ++mi)
                #pragma unroll
                for (int ni = 0; ni < 4; ++ni)
                    acc[mi][ni] = __builtin_amdgcn_mfma_f32_16x16x32_bf16(
                        af[mi], bfr[ni], acc[mi][ni], 0, 0, 0);
        }
        __syncthreads();
    }

    const float* bias  = (mat == 0) ? bq : (mat == 1) ? bk : bv;
    unsigned short* Ob = (mat == 0) ? Qb : (mat == 1) ? Kb : Vb;
    const int col0 = (ct & 1) * 128;          // col within the 256-wide output
    #pragma unroll
    for (int ni = 0; ni < 4; ++ni) {
        const int coll = col0 + wn * 64 + ni * 16 + (lane & 15);
        const float bc = bias[coll];
        #pragma unroll
        for (int mi = 0; mi < 4; ++mi) {
            const int lr0 = wm * 64 + mi * 16 + ((lane >> 4) << 2);
            #pragma unroll
            for (int r = 0; r < 4; ++r) {
                const int lr = lr0 + r;
                float val = acc[mi][ni][r] + bc;
                if (mat == 0)      val = gelu_exact(val) + 1.0f;
                else if (mat == 1) val = gelu_exact(val * mys[lr]) + 1.0f;
                else               val = val * mys[lr];
                Ob[(row0 + lr) * 256 + coll] = f2bf(val);
            }
        }
    }
}

// ----------------------------------------------------------- KV reduce ----
// grid (64, 16): x = m-chunk (256 rows), y = (b*4+h). Vector FMA outer
// product; fp32 atomic accumulation into KV[bh][d][e] and Ksum[bh][d].
__global__ __launch_bounds__(256) void kv_reduce(
    const unsigned short* __restrict__ Kb, const unsigned short* __restrict__ Vb,
    float* __restrict__ KV, float* __restrict__ Ksum)
{
    __shared__ float kf[16][64];
    __shared__ float vf[16][64];
    const int t = threadIdx.x;
    const int bh = blockIdx.y;
    const long base = (long)(bh >> 2) * SEQ * 256 + (bh & 3) * 64;
    const long m0 = (long)blockIdx.x * 256;
    const int d0 = (t >> 4) * 4, e0 = (t & 15) * 4;
    const int sr = t >> 4, swhich = (t >> 3) & 1, sseg = t & 7;
    float acc[4][4] = {};
    float ks[4] = {};
    for (int it = 0; it < 16; ++it) {
        const long row = m0 + it * 16 + sr;
        const unsigned short* src = (swhich ? Vb : Kb) + base + row * 256 + sseg * 8;
        const uint4 raw = *(const uint4*)src;
        const unsigned short* rh = (const unsigned short*)&raw;
        float* dst = swhich ? &vf[sr][sseg * 8] : &kf[sr][sseg * 8];
        #pragma unroll
        for (int j = 0; j < 8; ++j) dst[j] = bf2f(rh[j]);
        __syncthreads();
        #pragma unroll
        for (int mm = 0; mm < 16; ++mm) {
            const float4 kd = *(const float4*)&kf[mm][d0];
            const float4 ve = *(const float4*)&vf[mm][e0];
            const float k4[4] = {kd.x, kd.y, kd.z, kd.w};
            const float v4[4] = {ve.x, ve.y, ve.z, ve.w};
            #pragma unroll
            for (int i = 0; i < 4; ++i)
                #pragma unroll
                for (int j = 0; j < 4; ++j) acc[i][j] += k4[i] * v4[j];
            if ((t & 15) == 0) {
                #pragma unroll
                for (int i = 0; i < 4; ++i) ks[i] += k4[i];
            }
        }
        __syncthreads();
    }
    #pragma unroll
    for (int i = 0; i < 4; ++i)
        #pragma unroll
        for (int j = 0; j < 4; ++j)
            atomicAdd(&KV[((size_t)bh * 64 + d0 + i) * 64 + e0 + j], acc[i][j]);
    if ((t & 15) == 0) {
        #pragma unroll
        for (int i = 0; i < 4; ++i) atomicAdd(&Ksum[bh * 64 + d0 + i], ks[i]);
    }
}

// ---------------------------------------------------------------- attn ----
// grid (512): one 128-row tile; loops the 4 heads. attn = (Q@KV)*mx/denom.
__global__ __launch_bounds__(256) void attn_kernel(
    const unsigned short* __restrict__ Qb, const float* __restrict__ KV,
    const float* __restrict__ Ksum, const float* __restrict__ mx,
    unsigned short* __restrict__ Ab)
{
    __shared__ unsigned short Qs[128 * 64];
    __shared__ unsigned short KVT[64 * 64];
    __shared__ float ksh[64];
    __shared__ float sden[128];
    const int t = threadIdx.x;
    const long row0 = (long)blockIdx.x * 128;
    const int b = (int)(row0 >> 14);
    const int lane = t & 63, wave = t >> 6, wm = wave >> 1, wn = wave & 1;

    for (int h = 0; h < 4; ++h) {
        const int bh = b * 4 + h;
        // stage Q_h [128][64]
        #pragma unroll
        for (int it = 0; it < 4; ++it) {
            const int idx = it * 256 + t;
            const int r = idx >> 3, c8 = (idx & 7) * 8;
            const uint4 v = *(const uint4*)(Qb + (row0 + r) * 256 + h * 64 + c8);
            *(uint4*)&Qs[swz_us(r, c8 * 2)] = v;
        }
        // stage KV^T [e][d] (bf16, swizzled)
        {
            const int e = t & 63, dg = t >> 6;
            #pragma unroll
            for (int i = 0; i < 16; ++i) {
                const int d = dg * 16 + i;
                const float v = KV[((size_t)bh * 64 + d) * 64 + e];
                KVT[(e * 128 + ((d * 2) ^ ((e & 7) << 4))) >> 1] = f2bf(v);
            }
        }
        if (t < 64) ksh[t] = Ksum[bh * 64 + t];
        __syncthreads();
        // denom per row; sden = mask_x / denom
        if (t < 128) {
            float s = 0.0f;
            for (int d = 0; d < 64; ++d)
                s += bf2f(Qs[swz_us(t, d * 2)]) * ksh[d];
            sden[t] = mx[row0 + t] / s;
        }
        __syncthreads();
        // MFMA: per wave 64m x 32e, k = 64 (two K=32 steps)
        f32x4 acc[4][2];
        #pragma unroll
        for (int i = 0; i < 4; ++i) { acc[i][0] = (f32x4)0.0f; acc[i][1] = (f32x4)0.0f; }
        #pragma unroll
        for (int kk = 0; kk < 2; ++kk) {
            const int kbyte = kk * 64 + (lane >> 4) * 16;
            short8 af[4], bfr[2];
            #pragma unroll
            for (int mi = 0; mi < 4; ++mi) {
                const int r = wm * 64 + mi * 16 + (lane & 15);
                af[mi] = *(const short8*)&Qs[swz_us(r, kbyte)];
            }
            #pragma unroll
            for (int ni = 0; ni < 2; ++ni) {
                const int e = wn * 32 + ni * 16 + (lane & 15);
                bfr[ni] = *(const short8*)&KVT[swz_us(e, kbyte)];
            }
            #pragma unroll
            for (int mi = 0; mi < 4; ++mi)
                #pragma unroll
                for (int ni = 0; ni < 2; ++ni)
                    acc[mi][ni] = __builtin_amdgcn_mfma_f32_16x16x32_bf16(
                        af[mi], bfr[ni], acc[mi][ni], 0, 0, 0);
        }
        #pragma unroll
        for (int ni = 0; ni < 2; ++ni) {
            const int e = wn * 32 + ni * 16 + (lane & 15);
            #pragma unroll
            for (int mi = 0; mi < 4; ++mi) {
                const int lr0 = wm * 64 + mi * 16 + ((lane >> 4) << 2);
                #pragma unroll
                for (int r = 0; r < 4; ++r) {
                    const int lr = lr0 + r;
                    const float val = acc[mi][ni][r] * sden[lr];
                    Ab[(row0 + lr) * 256 + h * 64 + e] = f2bf(val);
                }
            }
        }
        __syncthreads();   // LDS reused next head
    }
}

// ------------------------------------------------------------ out proj ----
// m97 template, grid 1024 = 512 row-tiles x 2 col-tiles, XCD-swizzled.
__global__ __launch_bounds__(256) void proj_gemm(
    const unsigned short* __restrict__ Ab, const unsigned short* __restrict__ Wpt,
    const float* __restrict__ bp, float* __restrict__ out)
{
    __shared__ unsigned short As[128 * 64];
    __shared__ unsigned short Bs[128 * 64];
    const int t = threadIdx.x;
    const int nwg = 1024, phys = blockIdx.x;
    const int l = (phys & 7) * (nwg >> 3) + (phys >> 3);
    const int rt = l >> 1, ct = l & 1;
    const long row0 = (long)rt * 128;
    const int col0 = ct * 128;
    const int lane = t & 63, wave = t >> 6, wm = wave >> 1, wn = wave & 1;

    f32x4 acc[4][4];
    #pragma unroll
    for (int i = 0; i < 4; ++i)
        #pragma unroll
        for (int j = 0; j < 4; ++j) acc[i][j] = (f32x4)0.0f;

    for (int k0 = 0; k0 < 256; k0 += 64) {
        #pragma unroll
        for (int i = 0; i < 4; ++i) {
            const int c = i * 256 + t;
            gl_lds16(Ab + (row0 + (c >> 3)) * 256 + k0 + (c & 7) * 8, &As[c * 8]);
        }
        #pragma unroll
        for (int i = 0; i < 4; ++i) {
            const int c = i * 256 + t;
            gl_lds16(Wpt + (size_t)(col0 + (c >> 3)) * 256 + k0 + (c & 7) * 8, &Bs[c * 8]);
        }
        __syncthreads();
        #pragma unroll
        for (int kk = 0; kk < 2; ++kk) {
            short8 af[4], bfr[4];
            #pragma unroll
            for (int mi = 0; mi < 4; ++mi) {
                const int r = wm * 64 + mi * 16 + (lane & 15);
                af[mi] = *(const short8*)&As[r * 64 + kk * 32 + (lane >> 4) * 8];
            }
            #pragma unroll
            for (int ni = 0; ni < 4; ++ni) {
                const int n = wn * 64 + ni * 16 + (lane & 15);
                bfr[ni] = *(const short8*)&Bs[n * 64 + kk * 32 + (lane >> 4) * 8];
            }
            #pragma unroll
            for (int mi = 0; mi < 4; ++mi)
                #pragma unroll
                for (int ni = 0; ni < 4; ++ni)
                    acc[mi][ni] = __builtin_amdgcn_mfma_f32_16x16x32_bf16(
                        af[mi], bfr[ni], acc[mi][ni], 0, 0, 0);
        }
        __syncthreads();
    }
    #pragma unroll
    for (int ni = 0; ni < 4; ++ni) {
        const int coll = col0 + wn * 64 + ni * 16 + (lane & 15);
        const float bc = bp[coll];
        #pragma unroll
        for (int mi = 0; mi < 4; ++mi) {
            const int lr0 = wm * 64 + mi * 16 + ((lane >> 4) << 2);
            #pragma unroll
            for (int r = 0; r < 4; ++r) {
                const long grow = row0 + lr0 + r;
                out[grow * 256 + coll] = acc[mi][ni][r] + bc;
            }
        }
    }
}

// -------------------------------------------------------------- launch ----
extern "C" void kernel_launch(void* const* d_in, const int* in_sizes, int n_in,
                              void* d_out, int out_size, void* d_ws, size_t ws_size,
                              hipStream_t stream)
{
    (void)in_sizes; (void)n_in; (void)out_size; (void)ws_size;
    const float* x  = (const float*)d_in[0];
    const float* mx = (const float*)d_in[1];
    const float* my = (const float*)d_in[2];
    const float* Wq = (const float*)d_in[3];
    const float* bq = (const float*)d_in[4];
    const float* Wk = (const float*)d_in[5];
    const float* bk = (const float*)d_in[6];
    const float* Wv = (const float*)d_in[7];
    const float* bv = (const float*)d_in[8];
    const float* Wp = (const float*)d_in[9];
    const float* bp = (const float*)d_in[10];
    float* out = (float*)d_out;

    const size_t nelem = (size_t)4 * SEQ * CHN;      // 16,777,216
    char* w = (char*)d_ws;
    unsigned short* xb   = (unsigned short*)w; w += nelem * 2;
    unsigned short* Qb   = (unsigned short*)w; w += nelem * 2;
    unsigned short* Kb   = (unsigned short*)w; w += nelem * 2;
    unsigned short* Vb   = (unsigned short*)w; w += nelem * 2;
    unsigned short* Wcat = (unsigned short*)w; w += 768 * 256 * 2;
    unsigned short* Wpt  = (unsigned short*)w; w += 131072;
    float* KV   = (float*)w; w += 262144;
    float* Ksum = (float*)w; w += 4096;
    unsigned short* Ab = Kb;   // alias: Kb is dead after kv_reduce

    cvt_kernel<<<2048, 256, 0, stream>>>(x, xb);
    prep_kernel<<<256, 256, 0, stream>>>(Wq, Wk, Wv, Wp, Wcat, Wpt, KV, Ksum);
    qkv_gemm<<<3072, 256, 0, stream>>>(xb, my, Wcat, bq, bk, bv, Qb, Kb, Vb);
    kv_reduce<<<dim3(64, 16), 256, 0, stream>>>(Kb, Vb, KV, Ksum);
    attn_kernel<<<512, 256, 0, stream>>>(Qb, KV, Ksum, mx, Ab);
    proj_gemm<<<1024, 256, 0, stream>>>(Ab, Wpt, bp, out);
}

// Round 7
// 338.086 us; speedup vs baseline: 1.2318x; 1.0349x over previous
//
#include <hip/hip_runtime.h>
#include <hip/hip_bf16.h>
#include <cstdint>
#include <cstddef>

// Shapes fixed by the problem: B=4, N=16384, C=256, H=4, D=64.
#define SEQ   16384
#define CHN   256

typedef __attribute__((ext_vector_type(8))) short  short8;   // 8 bf16 (4 VGPRs)
typedef __attribute__((ext_vector_type(4))) float  f32x4;    // MFMA C/D

#define AS1 __attribute__((address_space(1)))
#define AS3 __attribute__((address_space(3)))
static __device__ __forceinline__ void gl_lds16(const void* g, void* l) {
    // async global->LDS, 16 B per lane; LDS dest = wave base + lane*16
    __builtin_amdgcn_global_load_lds((const AS1 void*)g, (AS3 void*)l, 16, 0, 0);
}

static __device__ __forceinline__ unsigned short f2bf(float f) {
    unsigned int u = __builtin_bit_cast(unsigned int, f);
    u += 0x7fffu + ((u >> 16) & 1u);            // round-to-nearest-even
    return (unsigned short)(u >> 16);
}
static __device__ __forceinline__ float bf2f(unsigned short h) {
    unsigned int u = ((unsigned int)h) << 16;
    return __builtin_bit_cast(float, u);
}
static __device__ __forceinline__ float gelu_exact(float x) {
    return 0.5f * x * (1.0f + erff(x * 0.70710678118654752f));
}
// XOR-swizzled ushort index for [R][64]-bf16 LDS tiles (attn Qs only).
static __device__ __forceinline__ int swz_us(int row, int kbyte) {
    return (row * 128 + (kbyte ^ ((row & 7) << 4))) >> 1;
}

// ------------------------------------------------------------- convert ----
__global__ __launch_bounds__(256) void cvt_kernel(
    const float* __restrict__ x, unsigned short* __restrict__ xb)
{
    const int t0 = blockIdx.x * 256 + threadIdx.x;
    #pragma unroll
    for (int i = 0; i < 4; ++i) {
        const long g = (long)t0 + (long)i * 524288;   // 8-elem group id
        const float4 a = *(const float4*)(x + g * 8);
        const float4 b = *(const float4*)(x + g * 8 + 4);
        uint4 pk;
        pk.x = (unsigned int)f2bf(a.x) | ((unsigned int)f2bf(a.y) << 16);
        pk.y = (unsigned int)f2bf(a.z) | ((unsigned int)f2bf(a.w) << 16);
        pk.z = (unsigned int)f2bf(b.x) | ((unsigned int)f2bf(b.y) << 16);
        pk.w = (unsigned int)f2bf(b.z) | ((unsigned int)f2bf(b.w) << 16);
        *(uint4*)(xb + g * 8) = pk;
    }
}

// ---------------------------------------------------------------- prep ----
__global__ __launch_bounds__(256) void prep_kernel(
    const float* __restrict__ Wq, const float* __restrict__ Wk,
    const float* __restrict__ Wv, const float* __restrict__ Wp,
    unsigned short* __restrict__ Wcat, unsigned short* __restrict__ Wpt,
    float* __restrict__ KV, float* __restrict__ Ksum)
{
    const int idx = blockIdx.x * 256 + threadIdx.x;   // 0..65535
    const int n = idx >> 8, k = idx & 255;
    const int src = k * 256 + n;                      // W^T[n][k] = W[k][n]
    Wcat[idx]          = f2bf(Wq[src]);
    Wcat[65536 + idx]  = f2bf(Wk[src]);
    Wcat[131072 + idx] = f2bf(Wv[src]);
    Wpt[idx]           = f2bf(Wp[src]);
    KV[idx] = 0.0f;                                   // 16*64*64
    if (idx < 1024) Ksum[idx] = 0.0f;
}

// ------------------------------------------------------------ QKV GEMM ----
// 128x128 tile, BK=64 double-buffered, ONE barrier per K-step (stage t+1
// issued before compute of t; __syncthreads drains). LDS chunk-swizzled
// via pre-swizzled global source (rule #21): LDS slot j of row r holds
// global 16B-chunk j^(r&7) -> ds_read_b128 2-way conflict instead of 16.
// Epilogue through LDS: Q written row-major; K/V written TRANSPOSED to
// Kt/Vt[bh][ch][m] with full-128B stores (kills 2x write amplification).
__global__ __launch_bounds__(256) void qkv_gemm(
    const unsigned short* __restrict__ xb, const float* __restrict__ my,
    const unsigned short* __restrict__ Wcat,
    const float* __restrict__ bq, const float* __restrict__ bk,
    const float* __restrict__ bv,
    unsigned short* __restrict__ Qb, unsigned short* __restrict__ Kt,
    unsigned short* __restrict__ Vt)
{
    __shared__ unsigned short As[2][128 * 64];   // 2 x 16 KB
    __shared__ unsigned short Bs[2][128 * 64];   // 2 x 16 KB
    __shared__ float mys[128];
    const int t = threadIdx.x;
    const int nwg = 3072, phys = blockIdx.x;
    const int l = (phys & 7) * (nwg >> 3) + (phys >> 3);   // XCD swizzle
    const int rt = l / 6, ct = l % 6;
    const long row0 = (long)rt * 128;
    const int  ncol0 = ct * 128;              // row in Wcat (fused col)
    const int  mat = ct >> 1;
    const int  col0 = (ct & 1) * 128;         // col within 256-wide output
    const int lane = t & 63, wave = t >> 6, wm = wave >> 1, wn = wave & 1;

    auto stage = [&](int buf, int k0) {
        #pragma unroll
        for (int i = 0; i < 4; ++i) {
            const int c = i * 256 + t;        // 0..1023
            const int row = c >> 3, j = (c & 7) ^ (row & 7);
            gl_lds16(xb + (row0 + row) * 256 + k0 + j * 8, &As[buf][c * 8]);
        }
        #pragma unroll
        for (int i = 0; i < 4; ++i) {
            const int c = i * 256 + t;
            const int row = c >> 3, j = (c & 7) ^ (row & 7);
            gl_lds16(Wcat + (size_t)(ncol0 + row) * 256 + k0 + j * 8, &Bs[buf][c * 8]);
        }
    };

    if (t < 128) mys[t] = my[row0 + t];

    f32x4 acc[4][4];
    #pragma unroll
    for (int i = 0; i < 4; ++i)
        #pragma unroll
        for (int j = 0; j < 4; ++j) acc[i][j] = (f32x4)0.0f;

    stage(0, 0);
    __syncthreads();

    #pragma unroll
    for (int s = 0; s < 4; ++s) {
        const int buf = s & 1;
        if (s < 3) stage(buf ^ 1, (s + 1) * 64);
        #pragma unroll
        for (int kk = 0; kk < 2; ++kk) {
            const int g = kk * 4 + (lane >> 4);     // logical 16B chunk
            short8 af[4], bfr[4];
            #pragma unroll
            for (int mi = 0; mi < 4; ++mi) {
                const int r = wm * 64 + mi * 16 + (lane & 15);
                af[mi] = *(const short8*)&As[buf][r * 64 + (g ^ (r & 7)) * 8];
            }
            #pragma unroll
            for (int ni = 0; ni < 4; ++ni) {
                const int n = wn * 64 + ni * 16 + (lane & 15);
                bfr[ni] = *(const short8*)&Bs[buf][n * 64 + (g ^ (n & 7)) * 8];
            }
            #pragma unroll
            for (int mi = 0; mi < 4; ++mi)
                #pragma unroll
                for (int ni = 0; ni < 4; ++ni)
                    acc[mi][ni] = __builtin_amdgcn_mfma_f32_16x16x32_bf16(
                        af[mi], bfr[ni], acc[mi][ni], 0, 0, 0);
        }
        __syncthreads();
    }

    // ---- epilogue through LDS (reuse As space, 32 KB) ----
    unsigned short* C = &As[0][0];
    const float* bias = (mat == 0) ? bq : (mat == 1) ? bk : bv;
    #pragma unroll
    for (int ni = 0; ni < 4; ++ni) {
        const int cl = wn * 64 + ni * 16 + (lane & 15);     // local col
        const float bc = bias[col0 + cl];
        #pragma unroll
        for (int mi = 0; mi < 4; ++mi) {
            const int lr0 = wm * 64 + mi * 16 + ((lane >> 4) << 2);
            #pragma unroll
            for (int r = 0; r < 4; ++r) {
                const int lr = lr0 + r;
                float val = acc[mi][ni][r] + bc;
                if (mat == 0)      val = gelu_exact(val) + 1.0f;
                else if (mat == 1) val = gelu_exact(val * mys[lr]) + 1.0f;
                else               val = val * mys[lr];
                if (mat == 0) {
                    C[lr * 128 + cl] = f2bf(val);            // row-major
                } else {
                    // transposed, XOR-swizzled: banks spread by col
                    C[(cl * 256 + ((lr * 2) ^ ((cl & 7) << 4))) >> 1] = f2bf(val);
                }
            }
        }
    }
    __syncthreads();

    if (mat == 0) {
        const int r = t >> 1, c0 = (t & 1) * 64;
        uint4* dst = (uint4*)(Qb + (row0 + r) * 256 + col0 + c0);
        const uint4* src = (const uint4*)&C[r * 128 + c0];
        #pragma unroll
        for (int q = 0; q < 8; ++q) dst[q] = src[q];
    } else {
        const int chl = t >> 1, mh = (t & 1) * 64;
        const int chg = col0 + chl, h = chg >> 6, d = chg & 63;
        const int b = (int)(row0 >> 14);
        const long m0 = (row0 & 16383) + mh;
        unsigned short* dstp = (mat == 1 ? Kt : Vt)
                             + ((size_t)(b * 4 + h) * 64 + d) * SEQ + m0;
        #pragma unroll
        for (int q = 0; q < 8; ++q) {
            const int byteoff = chl * 256 + ((mh * 2 + q * 16) ^ ((chl & 7) << 4));
            *(uint4*)(dstp + q * 8) = *(const uint4*)((const char*)C + byteoff);
        }
    }
}

// ------------------------------------------------------------- KV GEMM ----
// KV[bh][d][e] = sum_m Kt[bh][d][m] * Vt[bh][e][m]; Ksum[bh][d] folded in.
// grid (32 ksplit, 16 bh), 4 waves; wave w owns d-tile w (16 d's) x 4 e-tiles.
// Fragments load 16B-contiguous directly from global (Kt/Vt m-contiguous).
__global__ __launch_bounds__(256) void kv_gemm(
    const unsigned short* __restrict__ Kt, const unsigned short* __restrict__ Vt,
    float* __restrict__ KV, float* __restrict__ Ksum)
{
    const int t = threadIdx.x, lane = t & 63, w = t >> 6;
    const int bh = blockIdx.y;
    const long k0 = (long)blockIdx.x * 512;
    const unsigned short* Ka = Kt + ((size_t)bh * 64 + w * 16 + (lane & 15)) * SEQ;
    f32x4 acc[4];
    #pragma unroll
    for (int e = 0; e < 4; ++e) acc[e] = (f32x4)0.0f;
    float ksacc = 0.0f;

    for (int ks = 0; ks < 16; ++ks) {
        const long kk = k0 + ks * 32 + (lane >> 4) * 8;
        const short8 a = *(const short8*)(Ka + kk);
        #pragma unroll
        for (int j = 0; j < 8; ++j) ksacc += bf2f((unsigned short)a[j]);
        #pragma unroll
        for (int e = 0; e < 4; ++e) {
            const short8 b = *(const short8*)(Vt
                + ((size_t)bh * 64 + e * 16 + (lane & 15)) * SEQ + kk);
            acc[e] = __builtin_amdgcn_mfma_f32_16x16x32_bf16(a, b, acc[e], 0, 0, 0);
        }
    }
    // Ksum: lanes {l, l^16, l^32, l^48} share row d = w*16 + (lane&15)
    ksacc += __shfl_xor(ksacc, 16, 64);
    ksacc += __shfl_xor(ksacc, 32, 64);
    if (lane < 16) atomicAdd(&Ksum[bh * 64 + w * 16 + lane], ksacc);
    #pragma unroll
    for (int e = 0; e < 4; ++e)
        #pragma unroll
        for (int j = 0; j < 4; ++j)
            atomicAdd(&KV[((size_t)bh * 64 + w * 16 + (lane >> 4) * 4 + j) * 64
                          + e * 16 + (lane & 15)], acc[e][j]);
}

// ---------------------------------------------------------------- attn ----
__global__ __launch_bounds__(256) void attn_kernel(
    const unsigned short* __restrict__ Qb, const float* __restrict__ KV,
    const float* __restrict__ Ksum, const float* __restrict__ mx,
    unsigned short* __restrict__ Ab)
{
    __shared__ unsigned short Qs[128 * 64];
    __shared__ unsigned short KVT[64 * 64];
    __shared__ float ksh[64];
    __shared__ float sden[128];
    const int t = threadIdx.x;
    const long row0 = (long)blockIdx.x * 128;
    const int b = (int)(row0 >> 14);
    const int lane = t & 63, wave = t >> 6, wm = wave >> 1, wn = wave & 1;

    for (int h = 0; h < 4; ++h) {
        const int bh = b * 4 + h;
        // stage Q_h [128][64]
        #pragma unroll
        for (int it = 0; it < 4; ++it) {
            const int idx = it * 256 + t;
            const int r = idx >> 3, c8 = (idx & 7) * 8;
            const uint4 v = *(const uint4*)(Qb + (row0 + r) * 256 + h * 64 + c8);
            *(uint4*)&Qs[swz_us(r, c8 * 2)] = v;
        }
        // stage KV^T [e][d] (bf16, swizzled)
        {
            const int e = t & 63, dg = t >> 6;
            #pragma unroll
            for (int i = 0; i < 16; ++i) {
                const int d = dg * 16 + i;
                const float v = KV[((size_t)bh * 64 + d) * 64 + e];
                KVT[(e * 128 + ((d * 2) ^ ((e & 7) << 4))) >> 1] = f2bf(v);
            }
        }
        if (t < 64) ksh[t] = Ksum[bh * 64 + t];
        __syncthreads();
        // denom per row, wave-parallel: 2 threads/row, short8 reads
        {
            const int r = t >> 1, hf = t & 1;
            float s = 0.0f;
            #pragma unroll
            for (int c8 = 0; c8 < 4; ++c8) {
                const int ke = hf * 32 + c8 * 8;
                const short8 q8 = *(const short8*)&Qs[swz_us(r, ke * 2)];
                #pragma unroll
                for (int j = 0; j < 8; ++j)
                    s += bf2f((unsigned short)q8[j]) * ksh[ke + j];
            }
            s += __shfl_xor(s, 1, 64);
            if (hf == 0) sden[r] = mx[row0 + r] / s;
        }
        __syncthreads();
        // MFMA: per wave 64m x 32e, k = 64
        f32x4 acc[4][2];
        #pragma unroll
        for (int i = 0; i < 4; ++i) { acc[i][0] = (f32x4)0.0f; acc[i][1] = (f32x4)0.0f; }
        #pragma unroll
        for (int kk = 0; kk < 2; ++kk) {
            const int kbyte = kk * 64 + (lane >> 4) * 16;
            short8 af[4], bfr[2];
            #pragma unroll
            for (int mi = 0; mi < 4; ++mi) {
                const int r = wm * 64 + mi * 16 + (lane & 15);
                af[mi] = *(const short8*)&Qs[swz_us(r, kbyte)];
            }
            #pragma unroll
            for (int ni = 0; ni < 2; ++ni) {
                const int e = wn * 32 + ni * 16 + (lane & 15);
                bfr[ni] = *(const short8*)&KVT[swz_us(e, kbyte)];
            }
            #pragma unroll
            for (int mi = 0; mi < 4; ++mi)
                #pragma unroll
                for (int ni = 0; ni < 2; ++ni)
                    acc[mi][ni] = __builtin_amdgcn_mfma_f32_16x16x32_bf16(
                        af[mi], bfr[ni], acc[mi][ni], 0, 0, 0);
        }
        #pragma unroll
        for (int ni = 0; ni < 2; ++ni) {
            const int e = wn * 32 + ni * 16 + (lane & 15);
            #pragma unroll
            for (int mi = 0; mi < 4; ++mi) {
                const int lr0 = wm * 64 + mi * 16 + ((lane >> 4) << 2);
                #pragma unroll
                for (int r = 0; r < 4; ++r) {
                    const int lr = lr0 + r;
                    const float val = acc[mi][ni][r] * sden[lr];
                    Ab[(row0 + lr) * 256 + h * 64 + e] = f2bf(val);
                }
            }
        }
        __syncthreads();   // LDS reused next head
    }
}

// ------------------------------------------------------------ out proj ----
// Same BK=64 dbuf 1-barrier template; f32 epilogue stores are already
// 64B/instruction (full sectors), no LDS staging needed.
__global__ __launch_bounds__(256) void proj_gemm(
    const unsigned short* __restrict__ Ab, const unsigned short* __restrict__ Wpt,
    const float* __restrict__ bp, float* __restrict__ out)
{
    __shared__ unsigned short As[2][128 * 64];
    __shared__ unsigned short Bs[2][128 * 64];
    const int t = threadIdx.x;
    const int nwg = 1024, phys = blockIdx.x;
    const int l = (phys & 7) * (nwg >> 3) + (phys >> 3);
    const int rt = l >> 1, ct = l & 1;
    const long row0 = (long)rt * 128;
    const int col0 = ct * 128;
    const int lane = t & 63, wave = t >> 6, wm = wave >> 1, wn = wave & 1;

    auto stage = [&](int buf, int k0) {
        #pragma unroll
        for (int i = 0; i < 4; ++i) {
            const int c = i * 256 + t;
            const int row = c >> 3, j = (c & 7) ^ (row & 7);
            gl_lds16(Ab + (row0 + row) * 256 + k0 + j * 8, &As[buf][c * 8]);
        }
        #pragma unroll
        for (int i = 0; i < 4; ++i) {
            const int c = i * 256 + t;
            const int row = c >> 3, j = (c & 7) ^ (row & 7);
            gl_lds16(Wpt + (size_t)(col0 + row) * 256 + k0 + j * 8, &Bs[buf][c * 8]);
        }
    };

    f32x4 acc[4][4];
    #pragma unroll
    for (int i = 0; i < 4; ++i)
        #pragma unroll
        for (int j = 0; j < 4; ++j) acc[i][j] = (f32x4)0.0f;

    stage(0, 0);
    __syncthreads();

    #pragma unroll
    for (int s = 0; s < 4; ++s) {
        const int buf = s & 1;
        if (s < 3) stage(buf ^ 1, (s + 1) * 64);
        #pragma unroll
        for (int kk = 0; kk < 2; ++kk) {
            const int g = kk * 4 + (lane >> 4);
            short8 af[4], bfr[4];
            #pragma unroll
            for (int mi = 0; mi < 4; ++mi) {
                const int r = wm * 64 + mi * 16 + (lane & 15);
                af[mi] = *(const short8*)&As[buf][r * 64 + (g ^ (r & 7)) * 8];
            }
            #pragma unroll
            for (int ni = 0; ni < 4; ++ni) {
                const int n = wn * 64 + ni * 16 + (lane & 15);
                bfr[ni] = *(const short8*)&Bs[buf][n * 64 + (g ^ (n & 7)) * 8];
            }
            #pragma unroll
            for (int mi = 0; mi < 4; ++mi)
                #pragma unroll
                for (int ni = 0; ni < 4; ++ni)
                    acc[mi][ni] = __builtin_amdgcn_mfma_f32_16x16x32_bf16(
                        af[mi], bfr[ni], acc[mi][ni], 0, 0, 0);
        }
        __syncthreads();
    }
    #pragma unroll
    for (int ni = 0; ni < 4; ++ni) {
        const int coll = col0 + wn * 64 + ni * 16 + (lane & 15);
        const float bc = bp[coll];
        #pragma unroll
        for (int mi = 0; mi < 4; ++mi) {
            const int lr0 = wm * 64 + mi * 16 + ((lane >> 4) << 2);
            #pragma unroll
            for (int r = 0; r < 4; ++r) {
                const long grow = row0 + lr0 + r;
                out[grow * 256 + coll] = acc[mi][ni][r] + bc;
            }
        }
    }
}

// -------------------------------------------------------------- launch ----
extern "C" void kernel_launch(void* const* d_in, const int* in_sizes, int n_in,
                              void* d_out, int out_size, void* d_ws, size_t ws_size,
                              hipStream_t stream)
{
    (void)in_sizes; (void)n_in; (void)out_size; (void)ws_size;
    const float* x  = (const float*)d_in[0];
    const float* mx = (const float*)d_in[1];
    const float* my = (const float*)d_in[2];
    const float* Wq = (const float*)d_in[3];
    const float* bq = (const float*)d_in[4];
    const float* Wk = (const float*)d_in[5];
    const float* bk = (const float*)d_in[6];
    const float* Wv = (const float*)d_in[7];
    const float* bv = (const float*)d_in[8];
    const float* Wp = (const float*)d_in[9];
    const float* bp = (const float*)d_in[10];
    float* out = (float*)d_out;

    const size_t nelem = (size_t)4 * SEQ * CHN;      // 16,777,216
    char* w = (char*)d_ws;
    unsigned short* xb   = (unsigned short*)w; w += nelem * 2;
    unsigned short* Qb   = (unsigned short*)w; w += nelem * 2;
    unsigned short* Kt   = (unsigned short*)w; w += nelem * 2;   // [bh][d][m]
    unsigned short* Vt   = (unsigned short*)w; w += nelem * 2;   // [bh][e][m]
    unsigned short* Wcat = (unsigned short*)w; w += 768 * 256 * 2;
    unsigned short* Wpt  = (unsigned short*)w; w += 131072;
    float* KV   = (float*)w; w += 262144;
    float* Ksum = (float*)w; w += 4096;
    unsigned short* Ab = Kt;   // alias: Kt dead after kv_gemm

    cvt_kernel<<<2048, 256, 0, stream>>>(x, xb);
    prep_kernel<<<256, 256, 0, stream>>>(Wq, Wk, Wv, Wp, Wcat, Wpt, KV, Ksum);
    qkv_gemm<<<3072, 256, 0, stream>>>(xb, my, Wcat, bq, bk, bv, Qb, Kt, Vt);
    kv_gemm<<<dim3(32, 16), 256, 0, stream>>>(Kt, Vt, KV, Ksum);
    attn_kernel<<<512, 256, 0, stream>>>(Qb, KV, Ksum, mx, Ab);
    proj_gemm<<<1024, 256, 0, stream>>>(Ab, Wpt, bp, out);
}